// Round 6
// baseline (315.038 us; speedup 1.0000x reference)
//
#include <hip/hip_runtime.h>
#include <math.h>

#define NDIM 16
#define DELTA 1e-6f
#define LOG1MD (-1.0000005e-6f)   // log(1 - 1e-6)

// PROBE ROUND: two identical launches of the best (R3) kernel to measure the
// marginal (warm-cache) kernel cost. Second launch recomputes identical
// outputs -> bitwise idempotent, graph-capture safe.

__device__ __forceinline__ float dpp_xor1(float v) {
    return __int_as_float(__builtin_amdgcn_mov_dpp(__float_as_int(v), 0xB1, 0xF, 0xF, true)); // quad_perm [1,0,3,2]
}
__device__ __forceinline__ float dpp_xor2(float v) {
    return __int_as_float(__builtin_amdgcn_mov_dpp(__float_as_int(v), 0x4E, 0xF, 0xF, true)); // quad_perm [2,3,0,1]
}

__global__ __launch_bounds__(256, 8) void sigflow_kernel(
    const float* __restrict__ x,
    const float* __restrict__ logdet_in,
    const float* __restrict__ dsp,
    float* __restrict__ out_xnew,
    float* __restrict__ out_logdet,
    int D)
{
    const int b    = blockIdx.x;
    const int tid  = threadIdx.x;
    const int sub  = tid & 3;    // which float4 chunk of 16 components
    const int egrp = tid >> 2;   // element slot within block: 0..63

    float local_ld = 0.0f;

    #pragma unroll 2
    for (int d0 = 0; d0 < D; d0 += 64) {
        const int d = d0 + egrp;
        const size_t eidx = (size_t)b * D + d;
        const float* base = dsp + eidx * (size_t)(3 * NDIM);

        const float4 av = ((const float4*)(base))[sub];
        const float4 bv = ((const float4*)(base + NDIM))[sub];
        const float4 wv = ((const float4*)(base + 2 * NDIM))[sub];
        const float  xv = x[eidx];

        const float ar[4] = {av.x, av.y, av.z, av.w};
        const float br[4] = {bv.x, bv.y, bv.z, bv.w};
        const float wr[4] = {wv.x, wv.y, wv.z, wv.w};

        float s0 = 0.f, s1 = 0.f, s2 = 0.f, s3 = 0.f;
        #pragma unroll
        for (int k = 0; k < 4; ++k) {
            float z  = ar[k];
            float sp = fmaxf(z, 0.f) + __logf(1.f + __expf(-fabsf(z)));   // softplus

            float pre = fmaf(sp, xv, br[k]);
            float ep  = __expf(-fabsf(pre));
            float r   = __builtin_amdgcn_rcpf(1.f + ep);
            float sig  = (pre >= 0.f) ? r : ep * r;   // sigmoid(pre)
            float sigc = (pre >= 0.f) ? ep * r : r;   // sigmoid(-pre)

            float ew = __expf(wr[k]);                 // logits ~N(0,1): safe w/o max-pass
            s0 += ew;
            s1 = fmaf(ew, sig,  s1);
            s2 = fmaf(ew, sigc, s2);
            s3 = fmaf(ew * sp, sig * sigc, s3);       // exp(logj_k) = w*a*sig*(1-sig)
        }

        s0 += dpp_xor1(s0); s1 += dpp_xor1(s1); s2 += dpp_xor1(s2); s3 += dpp_xor1(s3);
        s0 += dpp_xor2(s0); s1 += dpp_xor2(s1); s2 += dpp_xor2(s2); s3 += dpp_xor2(s3);

        float rs   = __builtin_amdgcn_rcpf(s0);
        float lse  = __logf(s3 * rs);                 // logsumexp(logj) - logZ
        float xpre = s1 * rs;
        float omx  = s2 * rs;
        float xc   = fmaf(xpre, 1.f - DELTA, 0.5f * DELTA);
        float oxc  = fmaf(omx,  1.f - DELTA, 0.5f * DELTA);
        float lxc  = __logf(xc);
        float l1xc = __logf(oxc);

        if (sub == 0) out_xnew[eidx] = lxc - l1xc;
        local_ld += 0.25f * (lse + LOG1MD - lxc - l1xc);
    }

    #pragma unroll
    for (int off = 32; off > 0; off >>= 1)
        local_ld += __shfl_down(local_ld, off, 64);

    __shared__ float sred[4];
    if ((tid & 63) == 0) sred[tid >> 6] = local_ld;
    __syncthreads();
    if (tid == 0)
        out_logdet[b] = sred[0] + sred[1] + sred[2] + sred[3] + logdet_in[b];
}

extern "C" void kernel_launch(void* const* d_in, const int* in_sizes, int n_in,
                              void* d_out, int out_size, void* d_ws, size_t ws_size,
                              hipStream_t stream) {
    const float* x      = (const float*)d_in[0];
    const float* logdet = (const float*)d_in[1];
    const float* dsp    = (const float*)d_in[2];

    const int B = in_sizes[1];               // 2048
    const int D = in_sizes[0] / B;           // 512

    float* out_xnew   = (float*)d_out;
    float* out_logdet = out_xnew + (size_t)B * D;

    // PROBE: identical launch twice. Marginal cost of launch #2 = warm-cache
    // kernel time; read it off the total vs R5's 281.4 us baseline.
    sigflow_kernel<<<B, 256, 0, stream>>>(x, logdet, dsp, out_xnew, out_logdet, D);
    sigflow_kernel<<<B, 256, 0, stream>>>(x, logdet, dsp, out_xnew, out_logdet, D);
}